// Round 3
// baseline (1207.379 us; speedup 1.0000x reference)
//
#include <hip/hip_runtime.h>
#include <hip/hip_bf16.h>

#define BATCH   16
#define NPTS    4096
#define CIN     256
#define COUT    512
#define KNN     16
#define NOUT    1024
#define XOUT_ELEMS 8388608   // 16*1024*512
#define LDA     40           // padded LDS leading dim (bf16 elems)
#define GEMM_BLOCKS 2048     // 512 M-tiles x 4 N-tiles
#define GATHER_BLOCKS 8192   // 16384 output points, 2 per block

typedef __attribute__((ext_vector_type(4))) float f32x4;
typedef __attribute__((ext_vector_type(2))) float f32x2;
typedef __attribute__((ext_vector_type(8))) short bf16x8;

__device__ __forceinline__ unsigned short f2bf_rne(float f) {
    unsigned u = __float_as_uint(f);
    return (unsigned short)((u + 0x7FFFu + ((u >> 16) & 1u)) >> 16);
}
__device__ __forceinline__ float bf2f(unsigned short s) {
    return __uint_as_float(((unsigned)s) << 16);
}

// 6-step DPP max-reduce: lane 63 ends with the wave max (validated R1 on HW).
__device__ __forceinline__ float wave_max_dpp(float v) {
    int x, y;
    x = __float_as_int(v);
    y = __builtin_amdgcn_update_dpp(x, x, 0x111, 0xf, 0xf, false);
    v = fmaxf(v, __int_as_float(y)); x = __float_as_int(v);
    y = __builtin_amdgcn_update_dpp(x, x, 0x112, 0xf, 0xf, false);
    v = fmaxf(v, __int_as_float(y)); x = __float_as_int(v);
    y = __builtin_amdgcn_update_dpp(x, x, 0x114, 0xf, 0xf, false);
    v = fmaxf(v, __int_as_float(y)); x = __float_as_int(v);
    y = __builtin_amdgcn_update_dpp(x, x, 0x118, 0xf, 0xf, false);
    v = fmaxf(v, __int_as_float(y)); x = __float_as_int(v);
    y = __builtin_amdgcn_update_dpp(x, x, 0x142, 0xf, 0xf, false);
    v = fmaxf(v, __int_as_float(y)); x = __float_as_int(v);
    y = __builtin_amdgcn_update_dpp(x, x, 0x143, 0xf, 0xf, false);
    v = fmaxf(v, __int_as_float(y));
    return v;   // valid in lane 63
}

// One launch, three roles by blockIdx:
//   [0,16)            FPS, one block per batch (the critical path, ~550us)
//   [16,16+2048)      bf16 MFMA GEMM + BN + ReLU -> h  (publishes tile counter)
//   [2064,2064+8192)  gather+maxpool, 2 output points/block (spins on fid/cnt)
extern "C" __global__ void __launch_bounds__(256)
fused_all(const float* __restrict__ x, const float* __restrict__ p,
          const int* __restrict__ sid32, const float* __restrict__ W,
          const float* __restrict__ bias, const float* __restrict__ gamma,
          const float* __restrict__ beta, const float* __restrict__ rmean,
          const float* __restrict__ rvar, int* __restrict__ fid,
          unsigned* __restrict__ cnt, unsigned short* __restrict__ h,
          float* __restrict__ out)
{
    extern __shared__ char smem[];
    const int t = threadIdx.x;

    if (blockIdx.x < BATCH) {
        // ---------------- FPS: exact replica of numpy f32 arithmetic ----------------
#pragma clang fp contract(off)
        const int b = blockIdx.x;
        float* lx = (float*)smem;          // [4096]
        float* ly = lx + NPTS;
        float* lz = ly + NPTS;
        unsigned long long* warr = (unsigned long long*)(lz + NPTS); // [2][4] dbuf
        float* pout = out + XOUT_ELEMS + (size_t)b * NOUT * 3;

        const float* pb = p + (size_t)b * NPTS * 3;
        for (int l = t; l < NPTS * 3; l += 256) {
            float v = pb[l];
            int pi = l / 3;
            int c = l - pi * 3;
            if (c == 0) lx[pi] = v; else if (c == 1) ly[pi] = v; else lz[pi] = v;
        }
        __syncthreads();

        // contiguous ownership: thread t owns points [16t,16t+16); lowest lane ==
        // lowest point index, so ballot+ctz reproduces np.argmax first-occurrence.
        f32x2 px2[8], py2[8], pz2[8], d2[8];
        const int base = t << 4;
#pragma unroll
        for (int j = 0; j < 8; ++j) {
            px2[j] = *(const f32x2*)(lx + base + (j << 1));
            py2[j] = *(const f32x2*)(ly + base + (j << 1));
            pz2[j] = *(const f32x2*)(lz + base + (j << 1));
            d2[j]  = (f32x2){3.4028235e38f, 3.4028235e38f}; // min(FLT_MAX,d0)==d0
        }
        if (t == 0)
            __hip_atomic_store(&fid[b * NOUT], b * NPTS, __ATOMIC_RELAXED,
                               __HIP_MEMORY_SCOPE_AGENT);

        int winner = 0;
        for (int i = 1; i < NOUT; ++i) {
            float wx = lx[winner], wy = ly[winner], wz = lz[winner]; // LDS bcast
            if (t == 0) {   // p_out for previous winner; stores are fire-and-forget
                float* po = pout + (size_t)(i - 1) * 3;
                po[0] = wx; po[1] = wy; po[2] = wz;
            }
            f32x2 wx2 = {wx, wx}, wy2 = {wy, wy}, wz2 = {wz, wz};
            float bestd = -1.0f;
            int   bestj = 0;
#pragma unroll
            for (int j = 0; j < 8; ++j) {
                // np semantics: ((dx*dx + dy*dy) + dz*dz), RN, no fma (contract off).
                // v_pk_add/mul_f32 are per-half IEEE RN -> bit-identical to scalar.
                f32x2 dx = px2[j] - wx2;
                f32x2 dy = py2[j] - wy2;
                f32x2 dz = pz2[j] - wz2;
                f32x2 s  = ((dx * dx) + (dy * dy)) + (dz * dz);
                f32x2 nd;
                nd.x = fminf(d2[j].x, s.x);
                nd.y = fminf(d2[j].y, s.y);
                d2[j] = nd;
                bool g0 = nd.x > bestd;            // strict >: earliest index wins
                bestd = g0 ? nd.x : bestd;
                bestj = g0 ? (j << 1) : bestj;
                bool g1 = nd.y > bestd;
                bestd = g1 ? nd.y : bestd;
                bestj = g1 ? (j << 1) + 1 : bestj;
            }
            float vmax = wave_max_dpp(bestd);
            float wmax = __int_as_float(
                __builtin_amdgcn_readlane(__float_as_int(vmax), 63));
            unsigned long long msk = __ballot(bestd == wmax);
            int lead = (int)__builtin_ctzll(msk);
            int wbpi = __builtin_amdgcn_readlane(base + bestj, lead);
            // d>=0: f32 bits order-isomorphic as unsigned; low word breaks
            // cross-wave ties toward the LOWEST point index.
            unsigned long long key = ((unsigned long long)__float_as_uint(wmax) << 32)
                                   | (unsigned)(NPTS - 1 - wbpi);
            unsigned long long* wrow = warr + ((i & 1) << 2);  // dbuf: 1 barrier/iter
            if ((t & 63) == 0) wrow[t >> 6] = key;
            __syncthreads();
            unsigned long long k0 = wrow[0], k1 = wrow[1], k2 = wrow[2], k3 = wrow[3];
            if (k1 > k0) k0 = k1;
            if (k3 > k2) k2 = k3;
            if (k2 > k0) k0 = k2;
            winner = NPTS - 1 - (int)(unsigned)(k0 & 0xffffffffull);
            if (t == 0)
                __hip_atomic_store(&fid[b * NOUT + i], b * NPTS + winner,
                                   __ATOMIC_RELAXED, __HIP_MEMORY_SCOPE_AGENT);
        }
        if (t == 0) {   // final winner's coords
            float* po = pout + (size_t)(NOUT - 1) * 3;
            po[0] = lx[winner]; po[1] = ly[winner]; po[2] = lz[winner];
        }
    } else if (blockIdx.x < BATCH + GEMM_BLOCKS) {
        // ---------------- GEMM: h = relu(BN(x @ W^T + b)), bf16 MFMA ----------------
        const int bid = blockIdx.x - BATCH;
        const int bm = bid >> 2;           // 512 M-tiles of 128
        const int bn = bid & 3;            // 4 N-tiles of 128
        short* As = (short*)smem;          // [128][LDA] bf16
        short* Bs = As + 128 * LDA;        // [128][LDA] bf16 (W is [n][k] = B^T)

        const int lane = t & 63;
        const int wv = t >> 6;
        const int wm = wv >> 1, wn = wv & 1;   // 2x2 waves, 64x64 each
        const int quad = lane >> 4, l16 = lane & 15;
        const int m0 = bm * 128, n0 = bn * 128;

        f32x4 acc[4][4];
        const f32x4 zero = {0.0f, 0.0f, 0.0f, 0.0f};
#pragma unroll
        for (int a = 0; a < 4; ++a)
#pragma unroll
            for (int bb = 0; bb < 4; ++bb) acc[a][bb] = zero;

        const int srow = t >> 3;           // 0..31
        const int scol = (t & 7) << 2;     // 0,4,...,28

        for (int ks = 0; ks < 8; ++ks) {   // K = 256 in steps of 32
            const int k0 = ks * 32;
            __syncthreads();
#pragma unroll
            for (int it = 0; it < 4; ++it) {
                int row = srow + it * 32;
                float4 va = *(const float4*)(x + (size_t)(m0 + row) * CIN + k0 + scol);
                short4 pa = make_short4((short)f2bf_rne(va.x), (short)f2bf_rne(va.y),
                                        (short)f2bf_rne(va.z), (short)f2bf_rne(va.w));
                *(short4*)(As + row * LDA + scol) = pa;
                float4 vb = *(const float4*)(W + (size_t)(n0 + row) * CIN + k0 + scol);
                short4 pb2 = make_short4((short)f2bf_rne(vb.x), (short)f2bf_rne(vb.y),
                                         (short)f2bf_rne(vb.z), (short)f2bf_rne(vb.w));
                *(short4*)(Bs + row * LDA + scol) = pb2;
            }
            __syncthreads();
            bf16x8 af[4], bfr[4];
#pragma unroll
            for (int tm = 0; tm < 4; ++tm)
                af[tm] = *(const bf16x8*)(As + (wm * 64 + tm * 16 + l16) * LDA + quad * 8);
#pragma unroll
            for (int tn = 0; tn < 4; ++tn)
                bfr[tn] = *(const bf16x8*)(Bs + (wn * 64 + tn * 16 + l16) * LDA + quad * 8);
#pragma unroll
            for (int tm = 0; tm < 4; ++tm)
#pragma unroll
                for (int tn = 0; tn < 4; ++tn)
                    acc[tm][tn] = __builtin_amdgcn_mfma_f32_16x16x32_bf16(
                        af[tm], bfr[tn], acc[tm][tn], 0, 0, 0);
        }
#pragma unroll
        for (int tn = 0; tn < 4; ++tn) {
            int c = n0 + wn * 64 + tn * 16 + l16;
            float sc = gamma[c] / sqrtf(rvar[c] + 1e-5f);
            float sh = (bias[c] - rmean[c]) * sc + beta[c];
#pragma unroll
            for (int tm = 0; tm < 4; ++tm) {
                int rbase = m0 + wm * 64 + tm * 16 + quad * 4;
#pragma unroll
                for (int r = 0; r < 4; ++r) {
                    float v = fmaxf(acc[tm][tn][r] * sc + sh, 0.0f);
                    h[(size_t)(rbase + r) * COUT + c] = f2bf_rne(v);
                }
            }
        }
        // publish: all h stores of this block visible device-wide, then count tile
        __threadfence();
        __syncthreads();
        if (t == 0)
            __hip_atomic_fetch_add(cnt, 1u, __ATOMIC_RELEASE,
                                   __HIP_MEMORY_SCOPE_AGENT);
    } else {
        // ---------------- gather+maxpool: 2 output points per block ----------------
        const int gb = blockIdx.x - (BATCH + GEMM_BLOCKS);
        const int j0 = gb << 1;
        int* rows  = (int*)smem;           // [2][16]
        int* frows = rows + 32;            // [2]
        const int g = t >> 7, tl = t & 127;

        if (tl == 0) {
            if (g == 0) {   // wait for all GEMM tiles (h fully written)
                long guard = 0;
                unsigned c;
                do {
                    c = __hip_atomic_load(cnt, __ATOMIC_ACQUIRE,
                                          __HIP_MEMORY_SCOPE_AGENT);
                    if (c >= (unsigned)GEMM_BLOCKS) break;
                    __builtin_amdgcn_s_sleep(32);
                } while (++guard < (1 << 21));
            }
            long guard = 0;
            int v;
            do {            // wait for this point's FPS index
                v = __hip_atomic_load(&fid[j0 + g], __ATOMIC_RELAXED,
                                      __HIP_MEMORY_SCOPE_AGENT);
                if (v >= 0) break;
                __builtin_amdgcn_s_sleep(16);
            } while (++guard < (1 << 21));
            frows[g] = v;
            __threadfence();   // acquire side: drop stale L1/L2 lines before h reads
        }
        __syncthreads();
        const int frow = frows[g];
        // sid_euc may be int32 or int64 (JAX x64 ambiguity); int64 high words of
        // nonneg values < 2^31 are all zero -> sniff.
        bool is64 = (sid32[1] == 0) && (sid32[3] == 0) && (sid32[5] == 0);
        if (tl < KNN) {
            long long e = (long long)frow * KNN + tl;
            rows[g * KNN + tl] = is64 ? sid32[e * 2] : sid32[e];
        }
        __syncthreads();

        const int c4 = tl << 2;
        float m0 = -3.4028235e38f, m1 = m0, m2 = m0, m3 = m0;
#pragma unroll
        for (int k = 0; k < KNN; ++k) {
            const ushort4 v = *(const ushort4*)(h + (size_t)rows[g * KNN + k] * COUT + c4);
            m0 = fmaxf(m0, bf2f(v.x));
            m1 = fmaxf(m1, bf2f(v.y));
            m2 = fmaxf(m2, bf2f(v.z));
            m3 = fmaxf(m3, bf2f(v.w));
        }
        *(float4*)(out + (size_t)(j0 + g) * COUT + c4) = make_float4(m0, m1, m2, m3);
    }
}

extern "C" void kernel_launch(void* const* d_in, const int* in_sizes, int n_in,
                              void* d_out, int out_size, void* d_ws, size_t ws_size,
                              hipStream_t stream)
{
    const float* x     = (const float*)d_in[0];
    const float* p     = (const float*)d_in[1];
    const int*   sid   = (const int*)d_in[2];   // tid_euc (d_in[3]) unused by reference
    const float* W     = (const float*)d_in[4];
    const float* bias  = (const float*)d_in[5];
    const float* gamma = (const float*)d_in[6];
    const float* beta  = (const float*)d_in[7];
    const float* rmean = (const float*)d_in[8];
    const float* rvar  = (const float*)d_in[9];
    float* out = (float*)d_out;

    int*      fid = (int*)d_ws;                                  // [16384] @ 0
    unsigned* cnt = (unsigned*)((char*)d_ws + 65536);            // [1]
    unsigned short* h = (unsigned short*)((char*)d_ws + 65792);  // 65536x512 bf16

    // sentinel init (graph-capture-legal: async on stream)
    hipMemsetAsync(d_ws, 0xFF, 65536, stream);       // fid = -1
    hipMemsetAsync((char*)d_ws + 65536, 0, 4, stream); // cnt = 0

    const size_t lds = 3 * NPTS * 4 + 2 * 4 * 8;     // 49216 B (FPS needs most)
    hipLaunchKernelGGL(fused_all, dim3(BATCH + GEMM_BLOCKS + GATHER_BLOCKS),
                       dim3(256), lds, stream,
                       x, p, sid, W, bias, gamma, beta, rmean, rvar,
                       fid, cnt, h, out);
}

// Round 8
// 1005.605 us; speedup vs baseline: 1.2006x; 1.2006x over previous
//
#include <hip/hip_runtime.h>
#include <hip/hip_bf16.h>

#define BATCH   16
#define NPTS    4096
#define CIN     256
#define COUT    512
#define KNN     16
#define NOUT    1024
#define XOUT_ELEMS 8388608   // 16*1024*512
#define LDA     40           // 80B rows: 16B-aligned (known-good R1/R2)
#define DYN_LDS 49408        // FPS: 3*4096*4 + 256 (warr); GEMM uses 40960 of it

typedef __attribute__((ext_vector_type(4))) float f32x4;
typedef __attribute__((ext_vector_type(2))) float f32x2;
typedef __attribute__((ext_vector_type(8))) short bf16x8;

__device__ __forceinline__ unsigned short f2bf_rne(float f) {
    unsigned u = __float_as_uint(f);
    return (unsigned short)((u + 0x7FFFu + ((u >> 16) & 1u)) >> 16);
}
__device__ __forceinline__ float bf2f(unsigned short s) {
    return __uint_as_float(((unsigned)s) << 16);
}

// 6-step DPP max-reduce across 64 lanes; lane 63 ends with the max (HW-validated R1).
__device__ __forceinline__ float wave_max_dpp(float v) {
    int x, y;
    x = __float_as_int(v);
    y = __builtin_amdgcn_update_dpp(x, x, 0x111, 0xf, 0xf, false);
    v = fmaxf(v, __int_as_float(y)); x = __float_as_int(v);
    y = __builtin_amdgcn_update_dpp(x, x, 0x112, 0xf, 0xf, false);
    v = fmaxf(v, __int_as_float(y)); x = __float_as_int(v);
    y = __builtin_amdgcn_update_dpp(x, x, 0x114, 0xf, 0xf, false);
    v = fmaxf(v, __int_as_float(y)); x = __float_as_int(v);
    y = __builtin_amdgcn_update_dpp(x, x, 0x118, 0xf, 0xf, false);
    v = fmaxf(v, __int_as_float(y)); x = __float_as_int(v);
    y = __builtin_amdgcn_update_dpp(x, x, 0x142, 0xf, 0xf, false);
    v = fmaxf(v, __int_as_float(y)); x = __float_as_int(v);
    y = __builtin_amdgcn_update_dpp(x, x, 0x143, 0xf, 0xf, false);
    v = fmaxf(v, __int_as_float(y));
    return v;
}

// one u64-max DPP step; CTRL must be an immediate -> template parameter.
template <int CTRL>
__device__ __forceinline__ void dpp_u64_max_step(unsigned& klo, unsigned& khi) {
    unsigned olo = (unsigned)__builtin_amdgcn_update_dpp(
        (int)klo, (int)klo, CTRL, 0xf, 0xf, false);
    unsigned ohi = (unsigned)__builtin_amdgcn_update_dpp(
        (int)khi, (int)khi, CTRL, 0xf, 0xf, false);
    bool take = (ohi > khi) || (ohi == khi && olo > klo);
    klo = take ? olo : klo;
    khi = take ? ohi : khi;
}

// Kernel 1: grid 528 x 1024 threads. NO spins/gates/tickets — cannot hang.
//   blocks [0,16):   FPS at 16 waves, 4 pts/thread (the hypothesis under test)
//   blocks [16,528): GEMM, 2 groups x 512 thr, each group: two 128x128 tiles
extern "C" __global__ void __launch_bounds__(1024)
fps_gemm(const float* __restrict__ x, const float* __restrict__ p,
         const float* __restrict__ W, const float* __restrict__ bias,
         const float* __restrict__ gamma, const float* __restrict__ beta,
         const float* __restrict__ rmean, const float* __restrict__ rvar,
         int* __restrict__ fid, unsigned short* __restrict__ h,
         float* __restrict__ out)
{
    extern __shared__ char smem[];
    const int t = threadIdx.x;
    const int lane = t & 63;
    const int wv = t >> 6;

    if (blockIdx.x < BATCH) {
        // ---------------- FPS: exact replica of numpy f32 arithmetic ----------------
#pragma clang fp contract(off)
        const int b = blockIdx.x;
        float* lx = (float*)smem;          // [4096]
        float* ly = lx + NPTS;
        float* lz = ly + NPTS;
        unsigned long long* warr = (unsigned long long*)(lz + NPTS); // [2][16] dbuf
        float* pout = out + XOUT_ELEMS + (size_t)b * NOUT * 3;

        const float* pb = p + (size_t)b * NPTS * 3;
        for (int l = t; l < NPTS * 3; l += 1024) {
            float v = pb[l];
            int pi = l / 3;
            int c = l - pi * 3;
            if (c == 0) lx[pi] = v; else if (c == 1) ly[pi] = v; else lz[pi] = v;
        }
        __syncthreads();

        // thread t owns points [4t,4t+4) (contiguous): lowest lane == lowest point
        // index, so ballot+ctz reproduces np.argmax first-occurrence exactly.
        f32x2 px2[2], py2[2], pz2[2], d2[2];
        const int base = t << 2;
#pragma unroll
        for (int j = 0; j < 2; ++j) {
            px2[j] = *(const f32x2*)(lx + base + (j << 1));
            py2[j] = *(const f32x2*)(ly + base + (j << 1));
            pz2[j] = *(const f32x2*)(lz + base + (j << 1));
            d2[j]  = (f32x2){3.4028235e38f, 3.4028235e38f}; // min(FLT_MAX,d0)==d0
        }
        if (t == 0) fid[b * NOUT] = b * NPTS;

        int winner = 0;
        for (int i = 1; i < NOUT; ++i) {
            float wx = lx[winner], wy = ly[winner], wz = lz[winner]; // LDS bcast
            if (t == 0) {   // p_out of previous winner
                float* po = pout + (size_t)(i - 1) * 3;
                po[0] = wx; po[1] = wy; po[2] = wz;
            }
            f32x2 wx2 = {wx, wx}, wy2 = {wy, wy}, wz2 = {wz, wz};
            float bestd = -1.0f;
            int   bestj = 0;
#pragma unroll
            for (int j = 0; j < 2; ++j) {
                // np semantics: ((dx*dx + dy*dy) + dz*dz), RN, no fma (contract off)
                f32x2 dx = px2[j] - wx2;
                f32x2 dy = py2[j] - wy2;
                f32x2 dz = pz2[j] - wz2;
                f32x2 s  = ((dx * dx) + (dy * dy)) + (dz * dz);
                f32x2 nd;
                nd.x = fminf(d2[j].x, s.x);
                nd.y = fminf(d2[j].y, s.y);
                d2[j] = nd;
                bool g0 = nd.x > bestd;            // strict >: earliest idx wins
                bestd = g0 ? nd.x : bestd;
                bestj = g0 ? (j << 1) : bestj;
                bool g1 = nd.y > bestd;
                bestd = g1 ? nd.y : bestd;
                bestj = g1 ? (j << 1) + 1 : bestj;
            }
            float vmax = wave_max_dpp(bestd);
            float wmax = __int_as_float(
                __builtin_amdgcn_readlane(__float_as_int(vmax), 63));
            unsigned long long msk = __ballot(bestd == wmax);
            int lead = (int)__builtin_ctzll(msk);
            int wbpi = __builtin_amdgcn_readlane(base + bestj, lead);
            // d>=0: f32 bits order-isomorphic as unsigned; low word prefers
            // LOWEST point index on cross-wave ties.
            unsigned long long key = ((unsigned long long)__float_as_uint(wmax) << 32)
                                   | (unsigned)(NPTS - 1 - wbpi);
            unsigned long long* wrow = warr + ((i & 1) << 4);  // dbuf: 1 barrier/iter
            if (lane == 0) wrow[wv] = key;
            __syncthreads();
            // combine 16 wave-keys: 4-step DPP u64 max in each 16-lane row.
            unsigned long long kk = wrow[lane & 15];
            unsigned klo = (unsigned)kk, khi = (unsigned)(kk >> 32);
            dpp_u64_max_step<0x111>(klo, khi);   // row_shr:1
            dpp_u64_max_step<0x112>(klo, khi);   // row_shr:2
            dpp_u64_max_step<0x114>(klo, khi);   // row_shr:4
            dpp_u64_max_step<0x118>(klo, khi);   // row_shr:8
            unsigned wlo = (unsigned)__builtin_amdgcn_readlane((int)klo, 15);
            winner = NPTS - 1 - (int)wlo;
            if (t == 0) fid[b * NOUT + i] = b * NPTS + winner;
        }
        if (t == 0) {
            float* po = pout + (size_t)(NOUT - 1) * 3;
            po[0] = lx[winner]; po[1] = ly[winner]; po[2] = lz[winner];
        }
    } else {
        // ------- GEMM: static tiles. group (bid,g) does tiles (bid*2+g)*2+{0,1} ------
        const int bid = blockIdx.x - BATCH;       // 0..511
        const int g  = t >> 9;                    // 0..1
        const int ts = t & 511;
        short* As = (short*)(smem + g * 20480);   // [128][LDA]
        short* Bs = As + 128 * LDA;               // [128][LDA]

        const int sl  = ts & 63;
        const int swv = ts >> 6;                  // 0..7 within group
        const int wm = swv >> 1;                  // 0..3 (32-row slab)
        const int wn = swv & 1;                   // 0..1 (64-col slab)
        const int quad = sl >> 4, l16 = sl & 15;
        const int srow = ts >> 3;                 // 0..63
        const int scol = (ts & 7) << 2;           // 0..28

        for (int half = 0; half < 2; ++half) {
            const int tt = (bid * 2 + g) * 2 + half;   // 0..2047
            const int m0 = (tt >> 2) * 128, n0 = (tt & 3) * 128;

            f32x4 acc[2][4];
            const f32x4 zero = {0.0f, 0.0f, 0.0f, 0.0f};
#pragma unroll
            for (int a = 0; a < 2; ++a)
#pragma unroll
                for (int bb = 0; bb < 4; ++bb) acc[a][bb] = zero;

            for (int ks = 0; ks < 8; ++ks) {   // K=256 in steps of 32
                const int k0 = ks * 32;
                __syncthreads();   // both groups have identical barrier counts
#pragma unroll
                for (int it = 0; it < 2; ++it) {
                    int row = srow + it * 64;
                    float4 va = *(const float4*)(x + (size_t)(m0 + row) * CIN + k0 + scol);
                    short4 pa = make_short4((short)f2bf_rne(va.x), (short)f2bf_rne(va.y),
                                            (short)f2bf_rne(va.z), (short)f2bf_rne(va.w));
                    *(short4*)(As + row * LDA + scol) = pa;
                    float4 vb = *(const float4*)(W + (size_t)(n0 + row) * CIN + k0 + scol);
                    short4 pb2 = make_short4((short)f2bf_rne(vb.x), (short)f2bf_rne(vb.y),
                                             (short)f2bf_rne(vb.z), (short)f2bf_rne(vb.w));
                    *(short4*)(Bs + row * LDA + scol) = pb2;
                }
                __syncthreads();
                bf16x8 af[2], bfr[4];
#pragma unroll
                for (int tm = 0; tm < 2; ++tm)
                    af[tm] = *(const bf16x8*)(As + (wm * 32 + tm * 16 + l16) * LDA + quad * 8);
#pragma unroll
                for (int tn = 0; tn < 4; ++tn)
                    bfr[tn] = *(const bf16x8*)(Bs + (wn * 64 + tn * 16 + l16) * LDA + quad * 8);
#pragma unroll
                for (int tm = 0; tm < 2; ++tm)
#pragma unroll
                    for (int tn = 0; tn < 4; ++tn)
                        acc[tm][tn] = __builtin_amdgcn_mfma_f32_16x16x32_bf16(
                            af[tm], bfr[tn], acc[tm][tn], 0, 0, 0);
            }
#pragma unroll
            for (int tn = 0; tn < 4; ++tn) {
                int c = n0 + wn * 64 + tn * 16 + l16;
                float sc = gamma[c] / sqrtf(rvar[c] + 1e-5f);
                float sh = (bias[c] - rmean[c]) * sc + beta[c];
#pragma unroll
                for (int tm = 0; tm < 2; ++tm) {
                    int rbase = m0 + wm * 32 + tm * 16 + quad * 4;
#pragma unroll
                    for (int r = 0; r < 4; ++r) {
                        float v = fmaxf(acc[tm][tn][r] * sc + sh, 0.0f);
                        h[(size_t)(rbase + r) * COUT + c] = f2bf_rne(v);
                    }
                }
            }
            __syncthreads();   // don't restage while other group still reading
        }
    }
}

// Kernel 2: gather+maxpool (R2's known-good version, p_out writes removed)
extern "C" __global__ void __launch_bounds__(128)
gather_maxpool(const int* __restrict__ sid32, const int* __restrict__ fid,
               const unsigned short* __restrict__ h, float* __restrict__ out)
{
    const int j = blockIdx.x;     // 0..16383
    const int t = threadIdx.x;
    __shared__ int rows[KNN];
    const int frow = fid[j];
    // sid_euc may be int32 or int64 (JAX x64 ambiguity); int64 high words of
    // nonneg values < 2^31 are all zero -> sniff.
    bool is64 = (sid32[1] == 0) && (sid32[3] == 0) && (sid32[5] == 0);
    if (t < KNN) {
        long long e = (long long)frow * KNN + t;
        rows[t] = is64 ? sid32[e * 2] : sid32[e];
    }
    __syncthreads();

    const int c4 = t << 2;
    float m0 = -3.4028235e38f, m1 = m0, m2 = m0, m3 = m0;
#pragma unroll
    for (int k = 0; k < KNN; ++k) {
        const ushort4 v = *(const ushort4*)(h + (size_t)rows[k] * COUT + c4);
        m0 = fmaxf(m0, bf2f(v.x));
        m1 = fmaxf(m1, bf2f(v.y));
        m2 = fmaxf(m2, bf2f(v.z));
        m3 = fmaxf(m3, bf2f(v.w));
    }
    *(float4*)(out + (size_t)j * COUT + c4) = make_float4(m0, m1, m2, m3);
}

extern "C" void kernel_launch(void* const* d_in, const int* in_sizes, int n_in,
                              void* d_out, int out_size, void* d_ws, size_t ws_size,
                              hipStream_t stream)
{
    const float* x     = (const float*)d_in[0];
    const float* p     = (const float*)d_in[1];
    const int*   sid   = (const int*)d_in[2];   // tid_euc (d_in[3]) unused
    const float* W     = (const float*)d_in[4];
    const float* bias  = (const float*)d_in[5];
    const float* gamma = (const float*)d_in[6];
    const float* beta  = (const float*)d_in[7];
    const float* rmean = (const float*)d_in[8];
    const float* rvar  = (const float*)d_in[9];
    float* out = (float*)d_out;

    int* fid = (int*)d_ws;                                      // [16384] @ 0
    unsigned short* h = (unsigned short*)((char*)d_ws + 65792); // 65536x512 bf16

    hipLaunchKernelGGL(fps_gemm, dim3(BATCH + 512), dim3(1024), DYN_LDS, stream,
                       x, p, W, bias, gamma, beta, rmean, rvar, fid, h, out);
    hipLaunchKernelGGL(gather_maxpool, dim3(BATCH * NOUT), dim3(128), 0, stream,
                       sid, fid, h, out);
}

// Round 9
// 958.235 us; speedup vs baseline: 1.2600x; 1.0494x over previous
//
#include <hip/hip_runtime.h>
#include <hip/hip_bf16.h>

#define BATCH   16
#define NPTS    4096
#define CIN     256
#define COUT    512
#define KNN     16
#define NOUT    1024
#define XOUT_ELEMS 8388608   // 16*1024*512
#define LDA     40           // padded LDS leading dim (bf16 elems), known-good
#define DYN_LDS 49408        // FPS: 3*4096*4 + key slots; GEMM uses 40960

typedef __attribute__((ext_vector_type(4))) float f32x4;
typedef __attribute__((ext_vector_type(2))) float f32x2;
typedef __attribute__((ext_vector_type(8))) short bf16x8;
typedef unsigned long long u64;

__device__ __forceinline__ unsigned short f2bf_rne(float f) {
    unsigned u = __float_as_uint(f);
    return (unsigned short)((u + 0x7FFFu + ((u >> 16) & 1u)) >> 16);
}
__device__ __forceinline__ float bf2f(unsigned short s) {
    return __uint_as_float(((unsigned)s) << 16);
}

// 6-step DPP max-reduce across 64 lanes; lane 63 ends with the max (HW-validated R1).
__device__ __forceinline__ float wave_max_dpp(float v) {
    int x, y;
    x = __float_as_int(v);
    y = __builtin_amdgcn_update_dpp(x, x, 0x111, 0xf, 0xf, false);
    v = fmaxf(v, __int_as_float(y)); x = __float_as_int(v);
    y = __builtin_amdgcn_update_dpp(x, x, 0x112, 0xf, 0xf, false);
    v = fmaxf(v, __int_as_float(y)); x = __float_as_int(v);
    y = __builtin_amdgcn_update_dpp(x, x, 0x114, 0xf, 0xf, false);
    v = fmaxf(v, __int_as_float(y)); x = __float_as_int(v);
    y = __builtin_amdgcn_update_dpp(x, x, 0x118, 0xf, 0xf, false);
    v = fmaxf(v, __int_as_float(y)); x = __float_as_int(v);
    y = __builtin_amdgcn_update_dpp(x, x, 0x142, 0xf, 0xf, false);
    v = fmaxf(v, __int_as_float(y)); x = __float_as_int(v);
    y = __builtin_amdgcn_update_dpp(x, x, 0x143, 0xf, 0xf, false);
    v = fmaxf(v, __int_as_float(y));
    return v;
}

// Kernel 1: blocks [0,16) FPS (4 waves, barrier-FREE flag sync); [16,2064) GEMM.
extern "C" __global__ void __launch_bounds__(256)
fps_gemm(const float* __restrict__ x, const float* __restrict__ p,
         const float* __restrict__ W, const float* __restrict__ bias,
         const float* __restrict__ gamma, const float* __restrict__ beta,
         const float* __restrict__ rmean, const float* __restrict__ rvar,
         int* __restrict__ fid, unsigned short* __restrict__ h,
         float* __restrict__ out)
{
    extern __shared__ char smem[];
    const int t = threadIdx.x;
    const int lane = t & 63;
    const int wv = t >> 6;

    if (blockIdx.x < BATCH) {
        // ---------------- FPS: exact replica of numpy f32 arithmetic ----------------
#pragma clang fp contract(off)
        const int b = blockIdx.x;
        float* lx = (float*)smem;          // [4096]
        float* ly = lx + NPTS;
        float* lz = ly + NPTS;
        u64* keys = (u64*)(lz + NPTS);     // [2][4] parity-dbuf key slots
        float* pout = out + XOUT_ELEMS + (size_t)b * NOUT * 3;

        const float* pb = p + (size_t)b * NPTS * 3;
        for (int l = t; l < NPTS * 3; l += 256) {
            float v = pb[l];
            int pi = l / 3;
            int c = l - pi * 3;
            if (c == 0) lx[pi] = v; else if (c == 1) ly[pi] = v; else lz[pi] = v;
        }
        // init key slots with wrong-parity tags so garbage can't match:
        // odd slot (used by odd i) gets even tag 0; even slot gets odd tag 1.
        if (t < 4) {
            keys[4 + t] = (u64)(0u << 12);     // parity 1, tag 0 (even)
            keys[t]     = (u64)(1u << 12);     // parity 0, tag 1 (odd)
        }
        __syncthreads();   // the ONLY block barrier (after staging)

        // thread t owns points [16t,16t+16): lowest lane == lowest point index,
        // so ballot+ctz reproduces np.argmax first-occurrence exactly.
        f32x2 px2[8], py2[8], pz2[8], d2[8];
        const int base = t << 4;
#pragma unroll
        for (int j = 0; j < 8; ++j) {
            px2[j] = *(const f32x2*)(lx + base + (j << 1));
            py2[j] = *(const f32x2*)(ly + base + (j << 1));
            pz2[j] = *(const f32x2*)(lz + base + (j << 1));
            d2[j]  = (f32x2){3.4028235e38f, 3.4028235e38f}; // min(FLT_MAX,d0)==d0
        }
        if (t == 0) fid[b * NOUT] = b * NPTS;

        int winner = 0;
        for (int i = 1; i < NOUT; ++i) {
            float wx = lx[winner], wy = ly[winner], wz = lz[winner]; // LDS bcast
            if (t == 0) {   // p_out of previous winner (fire-and-forget)
                float* po = pout + (size_t)(i - 1) * 3;
                po[0] = wx; po[1] = wy; po[2] = wz;
            }
            f32x2 wx2 = {wx, wx}, wy2 = {wy, wy}, wz2 = {wz, wz};
            float bestd = -1.0f;
            int   bestj = 0;
#pragma unroll
            for (int j = 0; j < 8; ++j) {
                // np semantics: ((dx*dx + dy*dy) + dz*dz), RN, no fma (contract off)
                f32x2 dx = px2[j] - wx2;
                f32x2 dy = py2[j] - wy2;
                f32x2 dz = pz2[j] - wz2;
                f32x2 s  = ((dx * dx) + (dy * dy)) + (dz * dz);
                f32x2 nd;
                nd.x = fminf(d2[j].x, s.x);
                nd.y = fminf(d2[j].y, s.y);
                d2[j] = nd;
                bool g0 = nd.x > bestd;            // strict >: earliest idx wins
                bestd = g0 ? nd.x : bestd;
                bestj = g0 ? (j << 1) : bestj;
                bool g1 = nd.y > bestd;
                bestd = g1 ? nd.y : bestd;
                bestj = g1 ? (j << 1) + 1 : bestj;
            }
            // wave argmax (value via DPP, first-lane tie-break via ballot)
            float vmax = wave_max_dpp(bestd);
            float wmax = __int_as_float(
                __builtin_amdgcn_readlane(__float_as_int(vmax), 63));
            u64 msk = __ballot(bestd == wmax);
            int lead = (int)__builtin_ctzll(msk);
            int wbpi = __builtin_amdgcn_readlane(base + bestj, lead);
            // key: dist (primary, bits order-isomorphic for d>=0) | tag | inv-idx.
            // tag bits are EQUAL among same-iter keys -> never affect ordering;
            // stale keys are from iter i-2 -> tag mismatch (diff 2 mod 1024 != 0).
            const unsigned tag = (unsigned)i & 1023u;
            u64 key = ((u64)__float_as_uint(wmax) << 32)
                    | (tag << 12) | (unsigned)(NPTS - 1 - wbpi);
            u64* slot = keys + ((i & 1) << 2);
            if (lane == 0)
                __hip_atomic_store(&slot[wv], key, __ATOMIC_RELEASE,
                                   __HIP_MEMORY_SCOPE_WORKGROUP);
            // barrier-free combine: poll 4 slots until all carry this iter's tag
            u64 k0, k1, k2, k3;
            int guard = 0;
            for (;;) {
                k0 = __hip_atomic_load(&slot[0], __ATOMIC_ACQUIRE,
                                       __HIP_MEMORY_SCOPE_WORKGROUP);
                k1 = __hip_atomic_load(&slot[1], __ATOMIC_ACQUIRE,
                                       __HIP_MEMORY_SCOPE_WORKGROUP);
                k2 = __hip_atomic_load(&slot[2], __ATOMIC_ACQUIRE,
                                       __HIP_MEMORY_SCOPE_WORKGROUP);
                k3 = __hip_atomic_load(&slot[3], __ATOMIC_ACQUIRE,
                                       __HIP_MEMORY_SCOPE_WORKGROUP);
                unsigned t0 = ((unsigned)k0 >> 12) & 1023u;
                unsigned t1 = ((unsigned)k1 >> 12) & 1023u;
                unsigned t2 = ((unsigned)k2 >> 12) & 1023u;
                unsigned t3 = ((unsigned)k3 >> 12) & 1023u;
                if ((t0 == tag) & (t1 == tag) & (t2 == tag) & (t3 == tag)) break;
                if (++guard > (1 << 22)) break;   // finite: cannot hang
            }
            if (k1 > k0) k0 = k1;
            if (k3 > k2) k2 = k3;
            if (k2 > k0) k0 = k2;
            winner = NPTS - 1 - (int)(k0 & 0xFFFu);   // every lane decodes; no bcast
            if (t == 0) fid[b * NOUT + i] = b * NPTS + winner;
        }
        if (t == 0) {
            float* po = pout + (size_t)(NOUT - 1) * 3;
            po[0] = lx[winner]; po[1] = ly[winner]; po[2] = lz[winner];
        }
    } else {
        // ---------------- GEMM: h = relu(BN(x @ W^T + b)), bf16 MFMA ----------------
        const int bid = blockIdx.x - BATCH;
        const int bm = bid >> 2;           // 512 M-tiles of 128
        const int bn = bid & 3;            // 4 N-tiles of 128
        short* As = (short*)smem;          // [128][LDA]
        short* Bs = As + 128 * LDA;        // [128][LDA] (W is [n][k] = B^T)

        const int wm = wv >> 1, wn = wv & 1;   // 2x2 waves, 64x64 each
        const int quad = lane >> 4, l16 = lane & 15;
        const int m0 = bm * 128, n0 = bn * 128;

        f32x4 acc[4][4];
        const f32x4 zero = {0.0f, 0.0f, 0.0f, 0.0f};
#pragma unroll
        for (int a = 0; a < 4; ++a)
#pragma unroll
            for (int bb = 0; bb < 4; ++bb) acc[a][bb] = zero;

        const int srow = t >> 3;           // 0..31
        const int scol = (t & 7) << 2;     // 0..28

        for (int ks = 0; ks < 8; ++ks) {   // K=256 in steps of 32
            const int k0 = ks * 32;
            __syncthreads();
#pragma unroll
            for (int it = 0; it < 4; ++it) {
                int row = srow + it * 32;
                float4 va = *(const float4*)(x + (size_t)(m0 + row) * CIN + k0 + scol);
                short4 pa = make_short4((short)f2bf_rne(va.x), (short)f2bf_rne(va.y),
                                        (short)f2bf_rne(va.z), (short)f2bf_rne(va.w));
                *(short4*)(As + row * LDA + scol) = pa;
                float4 vb = *(const float4*)(W + (size_t)(n0 + row) * CIN + k0 + scol);
                short4 pb2 = make_short4((short)f2bf_rne(vb.x), (short)f2bf_rne(vb.y),
                                         (short)f2bf_rne(vb.z), (short)f2bf_rne(vb.w));
                *(short4*)(Bs + row * LDA + scol) = pb2;
            }
            __syncthreads();
            bf16x8 af[4], bfr[4];
#pragma unroll
            for (int tm = 0; tm < 4; ++tm)
                af[tm] = *(const bf16x8*)(As + (wm * 64 + tm * 16 + l16) * LDA + quad * 8);
#pragma unroll
            for (int tn = 0; tn < 4; ++tn)
                bfr[tn] = *(const bf16x8*)(Bs + (wn * 64 + tn * 16 + l16) * LDA + quad * 8);
#pragma unroll
            for (int tm = 0; tm < 4; ++tm)
#pragma unroll
                for (int tn = 0; tn < 4; ++tn)
                    acc[tm][tn] = __builtin_amdgcn_mfma_f32_16x16x32_bf16(
                        af[tm], bfr[tn], acc[tm][tn], 0, 0, 0);
        }
#pragma unroll
        for (int tn = 0; tn < 4; ++tn) {
            int c = n0 + wn * 64 + tn * 16 + l16;
            float sc = gamma[c] / sqrtf(rvar[c] + 1e-5f);
            float sh = (bias[c] - rmean[c]) * sc + beta[c];
#pragma unroll
            for (int tm = 0; tm < 4; ++tm) {
                int rbase = m0 + wm * 64 + tm * 16 + quad * 4;
#pragma unroll
                for (int r = 0; r < 4; ++r) {
                    float v = fmaxf(acc[tm][tn][r] * sc + sh, 0.0f);
                    h[(size_t)(rbase + r) * COUT + c] = f2bf_rne(v);
                }
            }
        }
    }
}

// Kernel 2: gather+maxpool (known-good R2/R7 version)
extern "C" __global__ void __launch_bounds__(128)
gather_maxpool(const int* __restrict__ sid32, const int* __restrict__ fid,
               const unsigned short* __restrict__ h, float* __restrict__ out)
{
    const int j = blockIdx.x;     // 0..16383
    const int t = threadIdx.x;
    __shared__ int rows[KNN];
    const int frow = fid[j];
    // sid_euc may be int32 or int64 (JAX x64 ambiguity); sniff high words.
    bool is64 = (sid32[1] == 0) && (sid32[3] == 0) && (sid32[5] == 0);
    if (t < KNN) {
        long long e = (long long)frow * KNN + t;
        rows[t] = is64 ? sid32[e * 2] : sid32[e];
    }
    __syncthreads();

    const int c4 = t << 2;
    float m0 = -3.4028235e38f, m1 = m0, m2 = m0, m3 = m0;
#pragma unroll
    for (int k = 0; k < KNN; ++k) {
        const ushort4 v = *(const ushort4*)(h + (size_t)rows[k] * COUT + c4);
        m0 = fmaxf(m0, bf2f(v.x));
        m1 = fmaxf(m1, bf2f(v.y));
        m2 = fmaxf(m2, bf2f(v.z));
        m3 = fmaxf(m3, bf2f(v.w));
    }
    *(float4*)(out + (size_t)j * COUT + c4) = make_float4(m0, m1, m2, m3);
}

extern "C" void kernel_launch(void* const* d_in, const int* in_sizes, int n_in,
                              void* d_out, int out_size, void* d_ws, size_t ws_size,
                              hipStream_t stream)
{
    const float* x     = (const float*)d_in[0];
    const float* p     = (const float*)d_in[1];
    const int*   sid   = (const int*)d_in[2];   // tid_euc (d_in[3]) unused
    const float* W     = (const float*)d_in[4];
    const float* bias  = (const float*)d_in[5];
    const float* gamma = (const float*)d_in[6];
    const float* beta  = (const float*)d_in[7];
    const float* rmean = (const float*)d_in[8];
    const float* rvar  = (const float*)d_in[9];
    float* out = (float*)d_out;

    int* fid = (int*)d_ws;                                      // [16384] @ 0
    unsigned short* h = (unsigned short*)((char*)d_ws + 65792); // 65536x512 bf16

    hipLaunchKernelGGL(fps_gemm, dim3(BATCH + 2048), dim3(256), DYN_LDS, stream,
                       x, p, W, bias, gamma, beta, rmean, rvar, fid, h, out);
    hipLaunchKernelGGL(gather_maxpool, dim3(BATCH * NOUT), dim3(128), 0, stream,
                       sid, fid, h, out);
}

// Round 10
// 733.012 us; speedup vs baseline: 1.6471x; 1.3073x over previous
//
#include <hip/hip_runtime.h>
#include <hip/hip_bf16.h>

#define BATCH   16
#define NPTS    4096
#define CIN     256
#define COUT    512
#define KNN     16
#define NOUT    1024
#define XOUT_ELEMS 8388608   // 16*1024*512
#define LDA     40           // padded LDS leading dim (bf16 elems), known-good
#define DYN_LDS 53312        // 3*4096*4 (xyz) + 64 (warr) + 4096 (wins)

typedef __attribute__((ext_vector_type(4))) float f32x4;
typedef __attribute__((ext_vector_type(2))) float f32x2;
typedef __attribute__((ext_vector_type(8))) short bf16x8;
typedef unsigned long long u64;

__device__ __forceinline__ unsigned short f2bf_rne(float f) {
    unsigned u = __float_as_uint(f);
    return (unsigned short)((u + 0x7FFFu + ((u >> 16) & 1u)) >> 16);
}
__device__ __forceinline__ float bf2f(unsigned short s) {
    return __uint_as_float(((unsigned)s) << 16);
}

// 6-step DPP max-reduce across 64 lanes; lane 63 ends with the max (HW-validated R1).
__device__ __forceinline__ float wave_max_dpp(float v) {
    int x, y;
    x = __float_as_int(v);
    y = __builtin_amdgcn_update_dpp(x, x, 0x111, 0xf, 0xf, false);
    v = fmaxf(v, __int_as_float(y)); x = __float_as_int(v);
    y = __builtin_amdgcn_update_dpp(x, x, 0x112, 0xf, 0xf, false);
    v = fmaxf(v, __int_as_float(y)); x = __float_as_int(v);
    y = __builtin_amdgcn_update_dpp(x, x, 0x114, 0xf, 0xf, false);
    v = fmaxf(v, __int_as_float(y)); x = __float_as_int(v);
    y = __builtin_amdgcn_update_dpp(x, x, 0x118, 0xf, 0xf, false);
    v = fmaxf(v, __int_as_float(y)); x = __float_as_int(v);
    y = __builtin_amdgcn_update_dpp(x, x, 0x142, 0xf, 0xf, false);
    v = fmaxf(v, __int_as_float(y)); x = __float_as_int(v);
    y = __builtin_amdgcn_update_dpp(x, x, 0x143, 0xf, 0xf, false);
    v = fmaxf(v, __int_as_float(y));
    return v;
}

// Kernel 1: blocks [0,16) FPS (R2 structure, NO global stores in the loop);
//           blocks [16,2064) GEMM.
extern "C" __global__ void __launch_bounds__(256)
fps_gemm(const float* __restrict__ x, const float* __restrict__ p,
         const float* __restrict__ W, const float* __restrict__ bias,
         const float* __restrict__ gamma, const float* __restrict__ beta,
         const float* __restrict__ rmean, const float* __restrict__ rvar,
         int* __restrict__ fid, unsigned short* __restrict__ h,
         float* __restrict__ out)
{
    extern __shared__ char smem[];
    const int t = threadIdx.x;
    const int lane = t & 63;
    const int wv = t >> 6;

    if (blockIdx.x < BATCH) {
        // ---------------- FPS: exact replica of numpy f32 arithmetic ----------------
#pragma clang fp contract(off)
        const int b = blockIdx.x;
        float* lx = (float*)smem;                        // [4096]
        float* ly = lx + NPTS;
        float* lz = ly + NPTS;
        u64* warr = (u64*)(smem + 49152);                // [2][4] parity dbuf keys
        int* wins = (int*)(smem + 49216);                // [1024] winner indices
        float* pout = out + XOUT_ELEMS + (size_t)b * NOUT * 3;

        const float* pb = p + (size_t)b * NPTS * 3;
        for (int l = t; l < NPTS * 3; l += 256) {
            float v = pb[l];
            int pi = l / 3;
            int c = l - pi * 3;
            if (c == 0) lx[pi] = v; else if (c == 1) ly[pi] = v; else lz[pi] = v;
        }
        if (t == 0) wins[0] = 0;       // idxs[0] = 0
        __syncthreads();

        // thread t owns points [16t,16t+16): lowest lane == lowest point index,
        // so ballot+ctz reproduces np.argmax first-occurrence exactly.
        f32x2 px2[8], py2[8], pz2[8], d2[8];
        const int base = t << 4;
#pragma unroll
        for (int j = 0; j < 8; ++j) {
            px2[j] = *(const f32x2*)(lx + base + (j << 1));
            py2[j] = *(const f32x2*)(ly + base + (j << 1));
            pz2[j] = *(const f32x2*)(lz + base + (j << 1));
            d2[j]  = (f32x2){3.4028235e38f, 3.4028235e38f}; // min(FLT_MAX,d0)==d0
        }

        int winner = 0;
        for (int i = 1; i < NOUT; ++i) {
            float wx = lx[winner], wy = ly[winner], wz = lz[winner]; // LDS bcast
            f32x2 wx2 = {wx, wx}, wy2 = {wy, wy}, wz2 = {wz, wz};
            float bestd = -1.0f;
            int   bestj = 0;
#pragma unroll
            for (int j = 0; j < 8; ++j) {
                // np semantics: ((dx*dx + dy*dy) + dz*dz), RN, no fma (contract off)
                f32x2 dx = px2[j] - wx2;
                f32x2 dy = py2[j] - wy2;
                f32x2 dz = pz2[j] - wz2;
                f32x2 s  = ((dx * dx) + (dy * dy)) + (dz * dz);
                f32x2 nd;
                nd.x = fminf(d2[j].x, s.x);
                nd.y = fminf(d2[j].y, s.y);
                d2[j] = nd;
                bool g0 = nd.x > bestd;            // strict >: earliest idx wins
                bestd = g0 ? nd.x : bestd;
                bestj = g0 ? (j << 1) : bestj;
                bool g1 = nd.y > bestd;
                bestd = g1 ? nd.y : bestd;
                bestj = g1 ? (j << 1) + 1 : bestj;
            }
            // wave argmax (value via DPP, first-lane tie-break via ballot)
            float vmax = wave_max_dpp(bestd);
            float wmax = __int_as_float(
                __builtin_amdgcn_readlane(__float_as_int(vmax), 63));
            u64 msk = __ballot(bestd == wmax);
            int lead = (int)__builtin_ctzll(msk);
            int wbpi = __builtin_amdgcn_readlane(base + bestj, lead);
            // d>=0: f32 bits order-isomorphic as unsigned; low word prefers
            // LOWEST point index on cross-wave ties.
            u64 key = ((u64)__float_as_uint(wmax) << 32)
                    | (unsigned)(NPTS - 1 - wbpi);
            u64* wrow = warr + ((i & 1) << 2);     // parity dbuf: 1 barrier/iter
            if (lane == 0) wrow[wv] = key;
            __syncthreads();                       // NO global stores pending: only
                                                   // LDS ops drain here (cheap)
            u64 k0 = wrow[0], k1 = wrow[1], k2 = wrow[2], k3 = wrow[3];
            if (k1 > k0) k0 = k1;
            if (k3 > k2) k2 = k3;
            if (k2 > k0) k0 = k2;
            winner = NPTS - 1 - (int)(unsigned)(k0 & 0xffffffffull);
            if (t == 0) wins[i] = winner;          // LDS only; drained next barrier
        }
        // epilogue: bulk-write fid and p_out (off the per-iteration critical path)
        __syncthreads();
        for (int i = t; i < NOUT; i += 256) {
            int w = wins[i];
            fid[b * NOUT + i] = b * NPTS + w;
            float* po = pout + (size_t)i * 3;
            po[0] = lx[w]; po[1] = ly[w]; po[2] = lz[w];
        }
    } else {
        // ---------------- GEMM: h = relu(BN(x @ W^T + b)), bf16 MFMA ----------------
        const int bid = blockIdx.x - BATCH;
        const int bm = bid >> 2;           // 512 M-tiles of 128
        const int bn = bid & 3;            // 4 N-tiles of 128
        short* As = (short*)smem;          // [128][LDA]
        short* Bs = As + 128 * LDA;        // [128][LDA] (W is [n][k] = B^T)

        const int wm = wv >> 1, wn = wv & 1;   // 2x2 waves, 64x64 each
        const int quad = lane >> 4, l16 = lane & 15;
        const int m0 = bm * 128, n0 = bn * 128;

        f32x4 acc[4][4];
        const f32x4 zero = {0.0f, 0.0f, 0.0f, 0.0f};
#pragma unroll
        for (int a = 0; a < 4; ++a)
#pragma unroll
            for (int bb = 0; bb < 4; ++bb) acc[a][bb] = zero;

        const int srow = t >> 3;           // 0..31
        const int scol = (t & 7) << 2;     // 0..28

        for (int ks = 0; ks < 8; ++ks) {   // K=256 in steps of 32
            const int k0 = ks * 32;
            __syncthreads();
#pragma unroll
            for (int it = 0; it < 4; ++it) {
                int row = srow + it * 32;
                float4 va = *(const float4*)(x + (size_t)(m0 + row) * CIN + k0 + scol);
                short4 pa = make_short4((short)f2bf_rne(va.x), (short)f2bf_rne(va.y),
                                        (short)f2bf_rne(va.z), (short)f2bf_rne(va.w));
                *(short4*)(As + row * LDA + scol) = pa;
                float4 vb = *(const float4*)(W + (size_t)(n0 + row) * CIN + k0 + scol);
                short4 pb2 = make_short4((short)f2bf_rne(vb.x), (short)f2bf_rne(vb.y),
                                         (short)f2bf_rne(vb.z), (short)f2bf_rne(vb.w));
                *(short4*)(Bs + row * LDA + scol) = pb2;
            }
            __syncthreads();
            bf16x8 af[4], bfr[4];
#pragma unroll
            for (int tm = 0; tm < 4; ++tm)
                af[tm] = *(const bf16x8*)(As + (wm * 64 + tm * 16 + l16) * LDA + quad * 8);
#pragma unroll
            for (int tn = 0; tn < 4; ++tn)
                bfr[tn] = *(const bf16x8*)(Bs + (wn * 64 + tn * 16 + l16) * LDA + quad * 8);
#pragma unroll
            for (int tm = 0; tm < 4; ++tm)
#pragma unroll
                for (int tn = 0; tn < 4; ++tn)
                    acc[tm][tn] = __builtin_amdgcn_mfma_f32_16x16x32_bf16(
                        af[tm], bfr[tn], acc[tm][tn], 0, 0, 0);
        }
#pragma unroll
        for (int tn = 0; tn < 4; ++tn) {
            int c = n0 + wn * 64 + tn * 16 + l16;
            float sc = gamma[c] / sqrtf(rvar[c] + 1e-5f);
            float sh = (bias[c] - rmean[c]) * sc + beta[c];
#pragma unroll
            for (int tm = 0; tm < 4; ++tm) {
                int rbase = m0 + wm * 64 + tm * 16 + quad * 4;
#pragma unroll
                for (int r = 0; r < 4; ++r) {
                    float v = fmaxf(acc[tm][tn][r] * sc + sh, 0.0f);
                    h[(size_t)(rbase + r) * COUT + c] = f2bf_rne(v);
                }
            }
        }
    }
}

// Kernel 2: gather+maxpool (known-good R2/R7 version)
extern "C" __global__ void __launch_bounds__(128)
gather_maxpool(const int* __restrict__ sid32, const int* __restrict__ fid,
               const unsigned short* __restrict__ h, float* __restrict__ out)
{
    const int j = blockIdx.x;     // 0..16383
    const int t = threadIdx.x;
    __shared__ int rows[KNN];
    const int frow = fid[j];
    // sid_euc may be int32 or int64 (JAX x64 ambiguity); sniff high words.
    bool is64 = (sid32[1] == 0) && (sid32[3] == 0) && (sid32[5] == 0);
    if (t < KNN) {
        long long e = (long long)frow * KNN + t;
        rows[t] = is64 ? sid32[e * 2] : sid32[e];
    }
    __syncthreads();

    const int c4 = t << 2;
    float m0 = -3.4028235e38f, m1 = m0, m2 = m0, m3 = m0;
#pragma unroll
    for (int k = 0; k < KNN; ++k) {
        const ushort4 v = *(const ushort4*)(h + (size_t)rows[k] * COUT + c4);
        m0 = fmaxf(m0, bf2f(v.x));
        m1 = fmaxf(m1, bf2f(v.y));
        m2 = fmaxf(m2, bf2f(v.z));
        m3 = fmaxf(m3, bf2f(v.w));
    }
    *(float4*)(out + (size_t)j * COUT + c4) = make_float4(m0, m1, m2, m3);
}

extern "C" void kernel_launch(void* const* d_in, const int* in_sizes, int n_in,
                              void* d_out, int out_size, void* d_ws, size_t ws_size,
                              hipStream_t stream)
{
    const float* x     = (const float*)d_in[0];
    const float* p     = (const float*)d_in[1];
    const int*   sid   = (const int*)d_in[2];   // tid_euc (d_in[3]) unused
    const float* W     = (const float*)d_in[4];
    const float* bias  = (const float*)d_in[5];
    const float* gamma = (const float*)d_in[6];
    const float* beta  = (const float*)d_in[7];
    const float* rmean = (const float*)d_in[8];
    const float* rvar  = (const float*)d_in[9];
    float* out = (float*)d_out;

    int* fid = (int*)d_ws;                                      // [16384] @ 0
    unsigned short* h = (unsigned short*)((char*)d_ws + 65792); // 65536x512 bf16

    hipLaunchKernelGGL(fps_gemm, dim3(BATCH + 2048), dim3(256), DYN_LDS, stream,
                       x, p, W, bias, gamma, beta, rmean, rvar, fid, h, out);
    hipLaunchKernelGGL(gather_maxpool, dim3(BATCH * NOUT), dim3(128), 0, stream,
                       sid, fid, h, out);
}